// Round 1
// baseline (104.022 us; speedup 1.0000x reference)
//
#include <hip/hip_runtime.h>
#include <math.h>

// Problem constants (fixed by reference setup_inputs)
#define N_TOT 8192
#define M_TOT 16384
#define EPS_N 1024      // M / N_EMB
#define N_EMB 16

#define LOG2E 1.4426950408889634f
#define LN2   0.6931471805599453f
#define EXP2(x) __builtin_amdgcn_exp2f(x)   // v_exp_f32
#define LOG2F_(x) __builtin_amdgcn_logf(x)  // v_log_f32 (log2)

// K1 tiling: product-grid factorization e_j = m_k + T*u_l  (j = k*1024 + l)
//   t_ij = A_ik + B_il,  P=2^A (8192x16), Q=2^B (8192x1024), S_kl = sum_i P_ik Q_il
#define BLOCK 256
#define IC    128            // i's per block
#define NICH  (N_TOT / IC)   // 64 i-chunks
#define LCH   128            // l's per block
#define NLCH  (EPS_N / LCH)  // 8 l-chunks

// Single fused dispatch: phase 1 = gemm partials (identical math to the
// 3-kernel version), then last-block-per-column election folds in the
// per-j combine (old kernel 2) and the final scalar assembly (old kernel 3).
__global__ __launch_bounds__(BLOCK) void fused_kernel(
    const float* __restrict__ z, const float* __restrict__ emb,
    const float* __restrict__ log_sigma, const float* __restrict__ eps,
    const float* __restrict__ temperature,
    float* __restrict__ part,          // [NICH][M_TOT] partial S
    float* __restrict__ colsum,        // [NLCH] per-column v-sums
    unsigned int* __restrict__ cnt,    // [NLCH] column counters + [NLCH]=final counter
    float* __restrict__ out)
{
    // per i: slots 0..3 = P[k=0..15] as float4s, slot 4 = (T*b0, T*b1, -, -)
    __shared__ float4 rows[IC * 5];              // 10 KB
    __shared__ float red[4][N_EMB * LCH];        // 32 KB, per-wave partials
    __shared__ float wsum[4];
    __shared__ unsigned int sflag;

    const int t  = threadIdx.x;
    const int lc = blockIdx.x;
    const int l0 = lc * LCH;
    const int ib = blockIdx.y;

    const float ls = log_sigma[0];
    const float T  = temperature[0];
    const float alpha = -0.5f * EXP2(LOG2E * (-2.0f * ls));  // -1/(2 sigma^2)
    const float La  = LOG2E * alpha;
    const float omT = 1.0f - T;

    // ---------------- Phase A: stage P-rows (identical to previous kernel 1)
    {
        const int il = t & (IC - 1);
        const int kh = t >> 7;                   // wave-uniform (waves 0,1 -> 0; 2,3 -> 1)
        const int i  = ib * IC + il;
        const float z0 = z[2 * i], z1 = z[2 * i + 1];
        const float c  = La * (z0 * z0 + z1 * z1);
        const float b0 = -2.0f * La * z0, b1 = -2.0f * La * z1;
        float4 pa, pb;
#pragma unroll
        for (int kk = 0; kk < 4; ++kk) {
            int k = kh * 8 + kk;
            float m0 = omT * emb[2 * k], m1 = omT * emb[2 * k + 1];
            ((float*)&pa)[kk] = EXP2(c + b0 * m0 + b1 * m1);   // P_ik
        }
#pragma unroll
        for (int kk = 0; kk < 4; ++kk) {
            int k = kh * 8 + 4 + kk;
            float m0 = omT * emb[2 * k], m1 = omT * emb[2 * k + 1];
            ((float*)&pb)[kk] = EXP2(c + b0 * m0 + b1 * m1);
        }
        rows[il * 5 + kh * 2]     = pa;
        rows[il * 5 + kh * 2 + 1] = pb;
        if (kh == 0)
            rows[il * 5 + 4] = make_float4(T * b0, T * b1, 0.0f, 0.0f);
    }

    // Each lane owns 2 l's: la = l0+lane, lb = la+64  (coalesced float2 loads)
    const int lane = t & 63;
    const int w    = t >> 6;
    const float2* eps2 = (const float2*)eps;
    const float2 ua = eps2[l0 + lane];
    const float2 ub = eps2[l0 + 64 + lane];

    __syncthreads();

    float sa[N_EMB] = {0.0f};
    float sb[N_EMB] = {0.0f};
    // Each wave reduces its private 32-i subrange; rows reads are wave-uniform (broadcast).
#pragma unroll 2
    for (int n = 0; n < IC / 4; ++n) {
        const int ir = w * (IC / 4) + n;
        float4 p0 = rows[ir * 5 + 0];
        float4 p1 = rows[ir * 5 + 1];
        float4 p2 = rows[ir * 5 + 2];
        float4 p3 = rows[ir * 5 + 3];
        float4 tb = rows[ir * 5 + 4];
        float qa = EXP2(fmaf(tb.y, ua.y, tb.x * ua.x));   // Q_i,la
        float qb = EXP2(fmaf(tb.y, ub.y, tb.x * ub.x));   // Q_i,lb
        float pk[16];
        *(float4*)&pk[0]  = p0; *(float4*)&pk[4]  = p1;
        *(float4*)&pk[8]  = p2; *(float4*)&pk[12] = p3;
#pragma unroll
        for (int k = 0; k < N_EMB; ++k) {
            sa[k] = fmaf(pk[k], qa, sa[k]);
            sb[k] = fmaf(pk[k], qb, sb[k]);
        }
    }

    // ---------------- Phase C: cross-wave reduce via LDS, write partials
#pragma unroll
    for (int k = 0; k < N_EMB; ++k) {
        red[w][k * LCH + lane]      = sa[k];
        red[w][k * LCH + 64 + lane] = sb[k];
    }
    __syncthreads();
#pragma unroll
    for (int r = 0; r < (N_EMB * LCH) / BLOCK; ++r) {
        const int e  = t + r * BLOCK;
        const float S = red[0][e] + red[1][e] + red[2][e] + red[3][e];
        const int k  = e >> 7;            // e / LCH
        const int lcl = e & (LCH - 1);
        part[ib * M_TOT + k * EPS_N + l0 + lcl] = S;
    }

    // ---------------- Election: last block of this l-column finishes it.
    // __syncthreads drains vmcnt for ALL waves (stores at least at L2);
    // __threadfence (agent scope) writes L2 back to the coherent point.
    __syncthreads();
    if (t == 0) {
        __threadfence();                                   // release
        unsigned int old = atomicAdd(&cnt[lc], 1u);        // device-scope
        sflag = (old == (unsigned int)(NICH - 1)) ? 1u : 0u;
    }
    __syncthreads();
    if (sflag == 0u) return;                               // not the finisher

    // ---------------- Phase 2 (old kernel 2), this block only, column lc:
    __threadfence();                                       // acquire: invalidate stale L1/L2
    float vsum = 0.0f;
#pragma unroll
    for (int r = 0; r < (N_EMB * LCH) / BLOCK; ++r) {      // 8: 2048 j's / 256 threads
        const int e  = t + r * BLOCK;
        const int k  = e >> 7;
        const int ll = e & (LCH - 1);
        const int j  = k * EPS_N + l0 + ll;
        float S = 0.0f;
#pragma unroll 8
        for (int ic = 0; ic < NICH; ++ic)
            S += part[ic * M_TOT + j];                     // coalesced across threads
        const float e0 = omT * emb[2 * k]     + T * eps[2 * (l0 + ll)];
        const float e1 = omT * emb[2 * k + 1] + T * eps[2 * (l0 + ll) + 1];
        const float g  = La * (e0 * e0 + e1 * e1);         // factored-out 2^g
        vsum += g + LOG2F_(S);                             // lse_j / ln2
    }
#pragma unroll
    for (int off = 32; off; off >>= 1) vsum += __shfl_down(vsum, off, 64);
    if (lane == 0) wsum[w] = vsum;
    __syncthreads();

    // ---------------- Phase 3 (old kernel 3): second election over columns
    if (t == 0) {
        colsum[lc] = wsum[0] + wsum[1] + wsum[2] + wsum[3];
        __threadfence();                                   // release colsum
        unsigned int o2 = atomicAdd(&cnt[NLCH], 1u);
        if (o2 == (unsigned int)(NLCH - 1)) {
            __threadfence();                               // acquire
            float v = 0.0f;
#pragma unroll
            for (int c = 0; c < NLCH; ++c) v += colsum[c]; // fixed order: deterministic
            const float sum_lse = v * LN2;
            // loss = -mean(lse) + 0.5*z_dim*(2*ls - 1) + log(n);  z_dim=2, n=8192
            out[0] = -sum_lse / (float)M_TOT + (2.0f * ls - 1.0f) + 9.010913347279288f;
        }
    }
}

extern "C" void kernel_launch(void* const* d_in, const int* in_sizes, int n_in,
                              void* d_out, int out_size, void* d_ws, size_t ws_size,
                              hipStream_t stream)
{
    const float* z    = (const float*)d_in[0];
    const float* emb  = (const float*)d_in[1];
    const float* lsig = (const float*)d_in[2];
    const float* eps  = (const float*)d_in[3];
    const float* temp = (const float*)d_in[4];

    // ws layout: [0,64) bytes = counters (zeroed each launch: workspace is
    // re-poisoned between iterations), then part (4 MB), then colsum.
    unsigned int* cnt = (unsigned int*)d_ws;               // NLCH + 1 counters
    float* part   = (float*)d_ws + 64;                     // 256 B offset, aligned
    float* colsum = part + (size_t)NICH * M_TOT;           // 8 floats

    hipMemsetAsync(d_ws, 0, 64, stream);                   // stream-ordered, capture-legal

    dim3 grid1(NLCH, NICH);                                // 8 x 64 = 512 blocks
    fused_kernel<<<grid1, BLOCK, 0, stream>>>(z, emb, lsig, eps, temp,
                                              part, colsum, cnt, (float*)d_out);
}

// Round 2
// 72.874 us; speedup vs baseline: 1.4274x; 1.4274x over previous
//
#include <hip/hip_runtime.h>
#include <math.h>

// Problem constants (fixed by reference setup_inputs)
#define N_TOT 8192
#define M_TOT 16384
#define EPS_N 1024      // M / N_EMB
#define N_EMB 16

#define LOG2E 1.4426950408889634f
#define LN2   0.6931471805599453f
#define EXP2(x) __builtin_amdgcn_exp2f(x)   // v_exp_f32
#define LOG2F_(x) __builtin_amdgcn_logf(x)  // v_log_f32 (log2)

// K1 tiling: product-grid factorization e_j = m_k + T*u_l  (j = k*1024 + l)
//   t_ij = A_ik + B_il,  P=2^A (8192x16), Q=2^B (8192x1024), S_kl = sum_i P_ik Q_il
#define BLOCK 256
#define IC    128            // i's per block
#define NICH  (N_TOT / IC)   // 64 i-chunks
#define LCH   128            // l's per block
#define NLCH  (EPS_N / LCH)  // 8 l-chunks

// Kernel 1: UNCHANGED from the proven 74 µs version. Plain stores, no fences —
// the kernel boundary provides cross-block coherence for `part` (round-1 lesson:
// intra-kernel __threadfence = buffer_wbl2 L2 writeback x512 blocks = +35 µs).
__global__ __launch_bounds__(BLOCK) void gemm_partial_kernel(
    const float* __restrict__ z, const float* __restrict__ emb,
    const float* __restrict__ log_sigma, const float* __restrict__ eps,
    const float* __restrict__ temperature, float* __restrict__ part)
{
    // per i: slots 0..3 = P[k=0..15] as float4s, slot 4 = (T*b0, T*b1, -, -)
    __shared__ float4 rows[IC * 5];              // 10 KB
    __shared__ float red[4][N_EMB * LCH];        // 32 KB, per-wave partials

    const int t  = threadIdx.x;
    const int l0 = blockIdx.x * LCH;
    const int ib = blockIdx.y;

    const float ls = log_sigma[0];
    const float T  = temperature[0];
    const float alpha = -0.5f * EXP2(LOG2E * (-2.0f * ls));  // -1/(2 sigma^2)
    const float La  = LOG2E * alpha;
    const float omT = 1.0f - T;

    // Phase A: stage P-rows. 256 threads cover 128 i's x 2 k-halves (8 exps each).
    {
        const int il = t & (IC - 1);
        const int kh = t >> 7;                   // wave-uniform (waves 0,1 -> 0; 2,3 -> 1)
        const int i  = ib * IC + il;
        const float z0 = z[2 * i], z1 = z[2 * i + 1];
        const float c  = La * (z0 * z0 + z1 * z1);
        const float b0 = -2.0f * La * z0, b1 = -2.0f * La * z1;
        float4 pa, pb;
#pragma unroll
        for (int kk = 0; kk < 4; ++kk) {
            int k = kh * 8 + kk;
            float m0 = omT * emb[2 * k], m1 = omT * emb[2 * k + 1];
            ((float*)&pa)[kk] = EXP2(c + b0 * m0 + b1 * m1);   // P_ik
        }
#pragma unroll
        for (int kk = 0; kk < 4; ++kk) {
            int k = kh * 8 + 4 + kk;
            float m0 = omT * emb[2 * k], m1 = omT * emb[2 * k + 1];
            ((float*)&pb)[kk] = EXP2(c + b0 * m0 + b1 * m1);
        }
        rows[il * 5 + kh * 2]     = pa;
        rows[il * 5 + kh * 2 + 1] = pb;
        if (kh == 0)
            rows[il * 5 + 4] = make_float4(T * b0, T * b1, 0.0f, 0.0f);
    }

    // Each lane owns 2 l's: la = l0+lane, lb = la+64  (coalesced float2 loads)
    const int lane = t & 63;
    const int w    = t >> 6;
    const float2* eps2 = (const float2*)eps;
    const float2 ua = eps2[l0 + lane];
    const float2 ub = eps2[l0 + 64 + lane];

    __syncthreads();

    float sa[N_EMB] = {0.0f};
    float sb[N_EMB] = {0.0f};
    // Each wave reduces its private 32-i subrange; rows reads are wave-uniform (broadcast).
#pragma unroll 2
    for (int n = 0; n < IC / 4; ++n) {
        const int ir = w * (IC / 4) + n;
        float4 p0 = rows[ir * 5 + 0];
        float4 p1 = rows[ir * 5 + 1];
        float4 p2 = rows[ir * 5 + 2];
        float4 p3 = rows[ir * 5 + 3];
        float4 tb = rows[ir * 5 + 4];
        float qa = EXP2(fmaf(tb.y, ua.y, tb.x * ua.x));   // Q_i,la
        float qb = EXP2(fmaf(tb.y, ub.y, tb.x * ub.x));   // Q_i,lb
        float pk[16];
        *(float4*)&pk[0]  = p0; *(float4*)&pk[4]  = p1;
        *(float4*)&pk[8]  = p2; *(float4*)&pk[12] = p3;
#pragma unroll
        for (int k = 0; k < N_EMB; ++k) {
            sa[k] = fmaf(pk[k], qa, sa[k]);
            sb[k] = fmaf(pk[k], qb, sb[k]);
        }
    }

    // Phase C: cross-wave reduce via LDS (conflict-free: lane-contiguous)
#pragma unroll
    for (int k = 0; k < N_EMB; ++k) {
        red[w][k * LCH + lane]      = sa[k];
        red[w][k * LCH + 64 + lane] = sb[k];
    }
    __syncthreads();
#pragma unroll
    for (int r = 0; r < (N_EMB * LCH) / BLOCK; ++r) {
        const int e  = t + r * BLOCK;
        const float S = red[0][e] + red[1][e] + red[2][e] + red[3][e];
        const int k  = e >> 7;            // e / LCH
        const int lc = e & (LCH - 1);
        part[ib * M_TOT + k * EPS_N + l0 + lc] = S;
    }
}

// Kernel 2: per-j combine + in-kernel final election (fuses old kernels 2+3).
// Only cross-block data INSIDE this kernel: 64 bsum floats + 1 counter, moved
// with agent-scope write-through atomics (sc0/sc1) — no L2 writeback fence.
__global__ __launch_bounds__(BLOCK) void reduce_final_kernel(
    const float* __restrict__ emb, const float* __restrict__ log_sigma,
    const float* __restrict__ eps, const float* __restrict__ temperature,
    const float* __restrict__ part, float* __restrict__ bsum,
    unsigned int* __restrict__ cnt, float* __restrict__ out)
{
    const int j = blockIdx.x * BLOCK + threadIdx.x;
    const float ls = log_sigma[0];
    const float T  = temperature[0];
    const float alpha = -0.5f * EXP2(LOG2E * (-2.0f * ls));

    float S = 0.0f;
#pragma unroll 16
    for (int ib = 0; ib < NICH; ++ib)
        S += part[ib * M_TOT + j];        // coalesced across threads; deep unroll for MLP

    const int k = j >> 10, l = j & (EPS_N - 1);
    const float omT = 1.0f - T;
    const float e0 = omT * emb[2 * k]     + T * eps[2 * l];
    const float e1 = omT * emb[2 * k + 1] + T * eps[2 * l + 1];
    const float g  = LOG2E * alpha * (e0 * e0 + e1 * e1);  // factored-out 2^g

    float v = g + LOG2F_(S);              // lse_j / ln2

#pragma unroll
    for (int off = 32; off; off >>= 1) v += __shfl_down(v, off, 64);
    __shared__ float wsum[BLOCK / 64];
    __shared__ unsigned int sdone;
    const int lane = threadIdx.x & 63, w = threadIdx.x >> 6;
    if (lane == 0) wsum[w] = v;
    __syncthreads();

    if (threadIdx.x == 0) {
        const float b = wsum[0] + wsum[1] + wsum[2] + wsum[3];
        // Write-through store to the coherent point (agent scope => sc0 sc1).
        __hip_atomic_store(&bsum[blockIdx.x], b, __ATOMIC_RELAXED,
                           __HIP_MEMORY_SCOPE_AGENT);
        // Order: bsum store must land before the counter bump becomes visible.
        // vmcnt(0) retires the write-through store at the coherent point;
        // no buffer_wbl2 needed (nothing relevant is dirty in L2).
        asm volatile("s_waitcnt vmcnt(0)" ::: "memory");
        const unsigned int old = __hip_atomic_fetch_add(
            &cnt[0], 1u, __ATOMIC_RELAXED, __HIP_MEMORY_SCOPE_AGENT);
        sdone = (old == (unsigned int)(M_TOT / BLOCK - 1)) ? 1u : 0u;
    }
    __syncthreads();
    if (sdone == 0u) return;              // not the last block

    // Last block: wave 0 sums the 64 block sums (fixed lane order: deterministic)
    if (threadIdx.x < 64) {
        float v2 = __hip_atomic_load(&bsum[threadIdx.x], __ATOMIC_RELAXED,
                                     __HIP_MEMORY_SCOPE_AGENT);
#pragma unroll
        for (int off = 32; off; off >>= 1) v2 += __shfl_down(v2, off, 64);
        if (threadIdx.x == 0) {
            const float sum_lse = v2 * LN2;   // sum_j lse_j
            // loss = -mean(lse) + 0.5*z_dim*(2*ls - 1) + log(n);  z_dim=2, n=8192
            out[0] = -sum_lse / (float)M_TOT + (2.0f * ls - 1.0f)
                     + 9.010913347279288f;
        }
    }
}

extern "C" void kernel_launch(void* const* d_in, const int* in_sizes, int n_in,
                              void* d_out, int out_size, void* d_ws, size_t ws_size,
                              hipStream_t stream)
{
    const float* z    = (const float*)d_in[0];
    const float* emb  = (const float*)d_in[1];
    const float* lsig = (const float*)d_in[2];
    const float* eps  = (const float*)d_in[3];
    const float* temp = (const float*)d_in[4];

    // ws layout: [0,64) counter (zeroed each launch), [64,320) bsum (64 floats,
    // fully overwritten before read), [512, 512+4MB) part.
    unsigned int* cnt = (unsigned int*)d_ws;
    float* bsum = (float*)d_ws + 16;               // offset 64 B
    float* part = (float*)d_ws + 128;              // offset 512 B

    hipMemsetAsync(d_ws, 0, 64, stream);           // stream-ordered, capture-legal

    dim3 grid1(NLCH, NICH);                        // 8 x 64 = 512 blocks
    gemm_partial_kernel<<<grid1, BLOCK, 0, stream>>>(z, emb, lsig, eps, temp, part);
    reduce_final_kernel<<<M_TOT / BLOCK, BLOCK, 0, stream>>>(
        emb, lsig, eps, temp, part, bsum, cnt, (float*)d_out);
}